// Round 1
// baseline (1879.011 us; speedup 1.0000x reference)
//
#include <hip/hip_runtime.h>

// Problem constants (compile-time, from reference)
#define NB   64      // batch B
#define LA   256     // L anchor points
#define DD   512     // feature dim
#define NCLS 10      // num classes
#define NREF 50
#define NNEG 100
#define MARGIN 10.0f
#define NITER 27     // 12 geometric eps steps (8 .. 0.00390625) + 15 @ 0.0025

// ---- workspace layout (float offsets) ----
#define OFF_CX   ((size_t)0)                      // cross cost  [64][256][500]
#define SZ_CX    ((size_t)64*256*500)
#define OFF_CAA  (OFF_CX + SZ_CX)                 // aa cost     [64][256][256]
#define SZ_CAA   ((size_t)64*256*256)
#define OFF_CNN  (OFF_CAA + SZ_CAA)               // nn cost     [64][100][100]
#define SZ_CNN   ((size_t)64*100*100)
#define OFF_CLN  (OFF_CNN + SZ_CNN)               // ln cost     [64][50][100]
#define SZ_CLN   ((size_t)64*50*100)
#define OFF_CGN  (OFF_CLN + SZ_CLN)               // gn cost     [64][50][100]
#define SZ_CGN   ((size_t)64*50*100)
#define OFF_CTT  (OFF_CGN + SZ_CGN)               // tt cost     [10][50][50]
#define SZ_CTT   ((size_t)10*50*50)
#define OFF_SQA  (OFF_CTT + SZ_CTT)               // 0.5*|anchor_row|^2  [64*256]
#define OFF_SQN  (OFF_SQA + (size_t)64*256)       // 0.5*|neg_row|^2     [64*100]
#define OFF_SQT  (OFF_SQN + (size_t)64*100)       // 0.5*|t0_row|^2      [500]
#define OFF_OTX  (OFF_SQT + (size_t)500)          // ot_cross [64*10]
#define OFF_OTAA (OFF_OTX + (size_t)640)
#define OFF_OTNN (OFF_OTAA + (size_t)64)
#define OFF_OTLN (OFF_OTNN + (size_t)64)
#define OFF_OTGN (OFF_OTLN + (size_t)64)
#define OFF_OTTT (OFF_OTGN + (size_t)64)

__device__ __forceinline__ float eps_at(int it) {
    // 8 * 2^-it for it<12, then blur^2 = 0.0025 (exact same f32 as python)
    return (it < 12) ? ldexpf(8.0f, -it) : 0.0025f;
}

// ---------------- K0: 0.5 * squared norms of every point row ----------------
__global__ __launch_bounds__(256) void sq_kernel(const float* __restrict__ anchor,
                                                 const float* __restrict__ neg,
                                                 const float* __restrict__ t0,
                                                 float* __restrict__ ws) {
    int gw   = (blockIdx.x * 256 + threadIdx.x) >> 6;  // one wave per row
    int lane = threadIdx.x & 63;
    const int nA = NB * LA, nN = NB * NNEG, nT = NCLS * NREF;
    if (gw >= nA + nN + nT) return;
    const float* row; float* outp;
    if (gw < nA)           { row = anchor + (size_t)gw * DD;          outp = ws + OFF_SQA + gw; }
    else if (gw < nA + nN) { int r = gw - nA;      row = neg + (size_t)r * DD; outp = ws + OFF_SQN + r; }
    else                   { int r = gw - nA - nN; row = t0  + (size_t)r * DD; outp = ws + OFF_SQT + r; }
    const float4* r4 = (const float4*)row;
    float4 u = r4[lane * 2], v = r4[lane * 2 + 1];
    float s = u.x*u.x + u.y*u.y + u.z*u.z + u.w*u.w
            + v.x*v.x + v.y*v.y + v.z*v.z + v.w*v.w;
    #pragma unroll
    for (int off = 1; off < 64; off <<= 1) s += __shfl_xor(s, off);
    if (lane == 0) *outp = 0.5f * s;
}

// ---------------- K1: all cost matrices, generic 64x64-tile fp32 GEMM ----------------
#define TS 64
#define KC 16
__global__ __launch_bounds__(256) void cost_kernel(const float* __restrict__ anchor,
                                                   const float* __restrict__ neg,
                                                   const float* __restrict__ t0,
                                                   const int* __restrict__ gneg,
                                                   float* __restrict__ ws) {
    __shared__ __align__(16) float As[KC][TS];
    __shared__ __align__(16) float Bs[KC][TS];
    int bid = blockIdx.x, tid = threadIdx.x;
    const float *X, *Y, *sqx, *sqy;
    float* Cout; int N, M, ldc, r0, c0;
    if (bid < 2048) {                     // cross: anchor[b] x t0_flat  (256 x 500)
        int b = bid >> 5, t = bid & 31; r0 = (t >> 3) * 64; c0 = (t & 7) * 64;
        X = anchor + (size_t)b * LA * DD; Y = t0; N = LA; M = 500; ldc = 500;
        Cout = ws + OFF_CX + (size_t)b * LA * 500;
        sqx = ws + OFF_SQA + b * LA; sqy = ws + OFF_SQT;
    } else if (bid < 3072) {              // aa: anchor[b] x anchor[b]  (256 x 256)
        int b2 = bid - 2048; int b = b2 >> 4, t = b2 & 15; r0 = (t >> 2) * 64; c0 = (t & 3) * 64;
        X = Y = anchor + (size_t)b * LA * DD; N = M = LA; ldc = LA;
        Cout = ws + OFF_CAA + (size_t)b * LA * LA;
        sqx = sqy = ws + OFF_SQA + b * LA;
    } else if (bid < 3328) {              // nn: neg[b] x neg[b]  (100 x 100)
        int b2 = bid - 3072; int b = b2 >> 2, t = b2 & 3; r0 = (t >> 1) * 64; c0 = (t & 1) * 64;
        X = Y = neg + (size_t)b * NNEG * DD; N = M = NNEG; ldc = NNEG;
        Cout = ws + OFF_CNN + (size_t)b * NNEG * NNEG;
        sqx = sqy = ws + OFF_SQN + b * NNEG;
    } else if (bid < 3456) {              // ln: t0[9] x neg[b]  (50 x 100)
        int b2 = bid - 3328; int b = b2 >> 1; r0 = 0; c0 = (b2 & 1) * 64;
        X = t0 + (size_t)9 * NREF * DD; Y = neg + (size_t)b * NNEG * DD;
        N = NREF; M = NNEG; ldc = NNEG;
        Cout = ws + OFF_CLN + (size_t)b * NREF * NNEG;
        sqx = ws + OFF_SQT + 9 * NREF; sqy = ws + OFF_SQN + b * NNEG;
    } else if (bid < 3584) {              // gn: t0[gneg[b]] x neg[b]  (50 x 100)
        int b2 = bid - 3456; int b = b2 >> 1; r0 = 0; c0 = (b2 & 1) * 64;
        int gc = gneg[b];
        X = t0 + (size_t)gc * NREF * DD; Y = neg + (size_t)b * NNEG * DD;
        N = NREF; M = NNEG; ldc = NNEG;
        Cout = ws + OFF_CGN + (size_t)b * NREF * NNEG;
        sqx = ws + OFF_SQT + gc * NREF; sqy = ws + OFF_SQN + b * NNEG;
    } else {                              // tt: t0[c] x t0[c]  (50 x 50)
        int c = bid - 3584; r0 = 0; c0 = 0;
        X = Y = t0 + (size_t)c * NREF * DD; N = M = NREF; ldc = NREF;
        Cout = ws + OFF_CTT + (size_t)c * NREF * NREF;
        sqx = sqy = ws + OFF_SQT + c * NREF;
    }
    int lr = tid >> 2, lk = (tid & 3) << 2;
    int tx = tid & 15, ty = tid >> 4;
    bool xok = (r0 + lr) < N, yok = (c0 + lr) < M;
    const float* xrow = X + (size_t)(r0 + lr) * DD;
    const float* yrow = Y + (size_t)(c0 + lr) * DD;
    float acc[4][4];
    #pragma unroll
    for (int a = 0; a < 4; a++)
        #pragma unroll
        for (int b = 0; b < 4; b++) acc[a][b] = 0.f;
    for (int k0 = 0; k0 < DD; k0 += KC) {
        float4 xa = xok ? *(const float4*)(xrow + k0 + lk) : make_float4(0,0,0,0);
        float4 ya = yok ? *(const float4*)(yrow + k0 + lk) : make_float4(0,0,0,0);
        __syncthreads();
        As[lk+0][lr]=xa.x; As[lk+1][lr]=xa.y; As[lk+2][lr]=xa.z; As[lk+3][lr]=xa.w;
        Bs[lk+0][lr]=ya.x; Bs[lk+1][lr]=ya.y; Bs[lk+2][lr]=ya.z; Bs[lk+3][lr]=ya.w;
        __syncthreads();
        #pragma unroll
        for (int k = 0; k < KC; k++) {
            const float4 av = *(const float4*)&As[k][ty << 2];
            const float4 bv = *(const float4*)&Bs[k][tx << 2];
            acc[0][0]=fmaf(av.x,bv.x,acc[0][0]); acc[0][1]=fmaf(av.x,bv.y,acc[0][1]);
            acc[0][2]=fmaf(av.x,bv.z,acc[0][2]); acc[0][3]=fmaf(av.x,bv.w,acc[0][3]);
            acc[1][0]=fmaf(av.y,bv.x,acc[1][0]); acc[1][1]=fmaf(av.y,bv.y,acc[1][1]);
            acc[1][2]=fmaf(av.y,bv.z,acc[1][2]); acc[1][3]=fmaf(av.y,bv.w,acc[1][3]);
            acc[2][0]=fmaf(av.z,bv.x,acc[2][0]); acc[2][1]=fmaf(av.z,bv.y,acc[2][1]);
            acc[2][2]=fmaf(av.z,bv.z,acc[2][2]); acc[2][3]=fmaf(av.z,bv.w,acc[2][3]);
            acc[3][0]=fmaf(av.w,bv.x,acc[3][0]); acc[3][1]=fmaf(av.w,bv.y,acc[3][1]);
            acc[3][2]=fmaf(av.w,bv.z,acc[3][2]); acc[3][3]=fmaf(av.w,bv.w,acc[3][3]);
        }
    }
    #pragma unroll
    for (int a = 0; a < 4; a++) {
        int n = r0 + (ty << 2) + a;
        if (n < N) {
            float sx = sqx[n];
            #pragma unroll
            for (int b = 0; b < 4; b++) {
                int m = c0 + (tx << 2) + b;
                if (m < M) Cout[(size_t)n * ldc + m] = sx + sqy[m] - acc[a][b];
            }
        }
    }
}

// ---------------- Sinkhorn LSE pass: out[o] = -eps*LSE_r( lw[r] + (other[r]-C[o,r])/eps )
// 16 lanes per output (16 groups per 256-thread block)
__device__ __forceinline__ void lse_pass(float* __restrict__ outv, const float* __restrict__ other,
                                         const float* __restrict__ lw, const float* __restrict__ Cs,
                                         int n_out, int Lred, int os, int rs,
                                         float eps, float inv_eps, int tid) {
    int grp = tid >> 4, j = tid & 15;
    for (int o = grp; o < n_out; o += 16) {
        int base = o * os;
        float m = -3.4e38f, s = 0.f;
        for (int r = j; r < Lred; r += 16) {
            float v  = lw[r] + (other[r] - Cs[base + r * rs]) * inv_eps;
            float mn = fmaxf(m, v);
            s = s * __expf(m - mn) + __expf(v - mn);
            m = mn;
        }
        #pragma unroll
        for (int off = 1; off < 16; off <<= 1) {
            float mo = __shfl_xor(m, off), so = __shfl_xor(s, off);
            float mn = fmaxf(m, mo);
            s = s * __expf(m - mn) + so * __expf(mo - mn);
            m = mn;
        }
        if (j == 0) outv[o] = -eps * (m + __logf(s));
    }
}

// ---------------- K2a: LDS-resident Sinkhorn (cross, nn, ln, gn, tt) ----------------
__global__ __launch_bounds__(256) void sinkhorn_lds(const float* __restrict__ weight,
                                                    float* __restrict__ ws) {
    __shared__ __align__(16) float Cs[256 * 51];               // max 13056 floats (cross)
    __shared__ __align__(16) float fpot[256], gpot[256], laS[256], lbS[256], awS[256];
    __shared__ float rbuf[4];
    int bid = blockIdx.x, tid = threadIdx.x;
    int N, M, Mp, ldc, coff = 0;
    size_t cgo, outoff;
    const float* aw_src = nullptr;
    float a_unif = 0.f, b_unif;
    if (bid < 640) {            // cross (i, c)
        int i = bid / 10, c = bid - 10 * (bid / 10);
        N = 256; M = 50; Mp = 51; ldc = 500; coff = c * 50;
        cgo = OFF_CX + (size_t)i * 256 * 500;
        aw_src = weight + (size_t)i * 256; b_unif = 1.0f / 50.0f;
        outoff = OFF_OTX + bid;
    } else if (bid < 704) {     // nn
        int i = bid - 640;
        N = 100; M = 100; Mp = 101; ldc = 100;
        cgo = OFF_CNN + (size_t)i * 10000;
        a_unif = 1.0f / 100.0f; b_unif = 1.0f / 100.0f;
        outoff = OFF_OTNN + i;
    } else if (bid < 768) {     // ln
        int i = bid - 704;
        N = 50; M = 100; Mp = 101; ldc = 100;
        cgo = OFF_CLN + (size_t)i * 5000;
        a_unif = 1.0f / 50.0f; b_unif = 1.0f / 100.0f;
        outoff = OFF_OTLN + i;
    } else if (bid < 832) {     // gn
        int i = bid - 768;
        N = 50; M = 100; Mp = 101; ldc = 100;
        cgo = OFF_CGN + (size_t)i * 5000;
        a_unif = 1.0f / 50.0f; b_unif = 1.0f / 100.0f;
        outoff = OFF_OTGN + i;
    } else {                    // tt
        int c = bid - 832;
        N = 50; M = 50; Mp = 51; ldc = 50;
        cgo = OFF_CTT + (size_t)c * 2500;
        a_unif = 1.0f / 50.0f; b_unif = 1.0f / 50.0f;
        outoff = OFF_OTTT + c;
    }
    // load C into LDS (stride padded to Mp)
    int NM = N * M;
    for (int e = tid; e < NM; e += 256) {
        int n = e / M, mm = e - n * M;
        Cs[n * Mp + mm] = ws[cgo + (size_t)n * ldc + coff + mm];
    }
    if (tid < N) {
        float w = aw_src ? aw_src[tid] : a_unif;
        awS[tid] = w;
        laS[tid] = (w > 0.f) ? __logf(fmaxf(w, 1e-30f)) : -1e9f;
        fpot[tid] = 0.f;
    }
    if (tid < M) { lbS[tid] = __logf(b_unif); gpot[tid] = 0.f; }
    __syncthreads();

    for (int it = 0; it < NITER; ++it) {
        float eps = eps_at(it);
        float inv_eps = 1.0f / eps;
        lse_pass(fpot, gpot, lbS, Cs, N, M, Mp, 1, eps, inv_eps, tid);   // f update
        __syncthreads();
        lse_pass(gpot, fpot, laS, Cs, M, N, 1, Mp, eps, inv_eps, tid);   // g update
        __syncthreads();
    }
    float contrib = 0.f;
    if (tid < N) contrib += awS[tid] * fpot[tid];
    if (tid < M) contrib += b_unif * gpot[tid];
    #pragma unroll
    for (int off = 1; off < 64; off <<= 1) contrib += __shfl_xor(contrib, off);
    if ((tid & 63) == 0) rbuf[tid >> 6] = contrib;
    __syncthreads();
    if (tid == 0) ws[outoff] = rbuf[0] + rbuf[1] + rbuf[2] + rbuf[3];
}

// ---------------- K2b: symmetric streaming Sinkhorn for aa (C in global, L2-resident) ----
__global__ __launch_bounds__(1024) void sinkhorn_aa(const float* __restrict__ weight,
                                                    float* __restrict__ ws) {
    __shared__ __align__(16) float h[256], hnew[256], laS[256], awS[256], fsave[256];
    __shared__ float rbuf[16];
    int i = blockIdx.x, tid = threadIdx.x;
    const float* Cg = ws + OFF_CAA + (size_t)i * LA * LA;
    if (tid < LA) {
        float w = weight[(size_t)i * LA + tid];
        awS[tid] = w;
        laS[tid] = (w > 0.f) ? __logf(fmaxf(w, 1e-30f)) : -1e9f;
        h[tid] = 0.f;
    }
    __syncthreads();
    int wid = tid >> 6, lane = tid & 63;
    // symmetric case: f,g iteration is one chain h <- T_eps(h), 54 applications
    for (int app = 0; app < 54; ++app) {
        float eps = eps_at(app >> 1);
        float inv_eps = 1.0f / eps;
        for (int n = wid; n < LA; n += 16) {
            const float4* Crow4 = (const float4*)(Cg + (size_t)n * LA);
            float4 cv = Crow4[lane];
            float4 hv = *(const float4*)&h[lane << 2];
            float4 lv = *(const float4*)&laS[lane << 2];
            float m = -3.4e38f, s = 0.f;
            { float v = lv.x + (hv.x - cv.x) * inv_eps; float mn = fmaxf(m, v); s = s * __expf(m - mn) + __expf(v - mn); m = mn; }
            { float v = lv.y + (hv.y - cv.y) * inv_eps; float mn = fmaxf(m, v); s = s * __expf(m - mn) + __expf(v - mn); m = mn; }
            { float v = lv.z + (hv.z - cv.z) * inv_eps; float mn = fmaxf(m, v); s = s * __expf(m - mn) + __expf(v - mn); m = mn; }
            { float v = lv.w + (hv.w - cv.w) * inv_eps; float mn = fmaxf(m, v); s = s * __expf(m - mn) + __expf(v - mn); m = mn; }
            #pragma unroll
            for (int off = 1; off < 64; off <<= 1) {
                float mo = __shfl_xor(m, off), so = __shfl_xor(s, off);
                float mn = fmaxf(m, mo);
                s = s * __expf(m - mn) + so * __expf(mo - mn);
                m = mn;
            }
            if (lane == 0) hnew[n] = -eps * (m + __logf(s));
        }
        __syncthreads();
        if (tid < LA) {
            if (app == 52) fsave[tid] = hnew[tid];  // f_final = h_53 (result of app 52)
            h[tid] = hnew[tid];
        }
        __syncthreads();
    }
    float contrib = (tid < LA) ? awS[tid] * (fsave[tid] + h[tid]) : 0.f;
    #pragma unroll
    for (int off = 1; off < 64; off <<= 1) contrib += __shfl_xor(contrib, off);
    if (lane == 0) rbuf[wid] = contrib;
    __syncthreads();
    if (tid == 0) {
        float s = 0.f;
        #pragma unroll
        for (int q = 0; q < 16; q++) s += rbuf[q];
        ws[OFF_OTAA + i] = s;
    }
}

// ---------------- K3: final loss assembly ----------------
__global__ void assemble_kernel(const int* __restrict__ grade, const int* __restrict__ gneg,
                                const float* __restrict__ ws, float* __restrict__ out) {
    int i = threadIdx.x;   // 64 threads, one wave
    float total = 0.f;
    if (i < 64) {
        float aa  = ws[OFF_OTAA + i];
        float nn  = ws[OFF_OTNN + i];
        float lnv = ws[OFF_OTLN + i];
        float gnv = ws[OFF_OTGN + i];
        int g  = grade[i];
        int gi = gneg[i];
        float tt9 = ws[OFF_OTTT + 9];
        float ttg = ws[OFF_OTTT + gi];
        float Slast = lnv - 0.5f * tt9 - 0.5f * nn;
        float Sgn   = gnv - 0.5f * ttg - 0.5f * nn;
        float Sv[10];
        #pragma unroll
        for (int k = 0; k < 10; k++)
            Sv[k] = ws[OFF_OTX + i * 10 + k] - 0.5f * aa - 0.5f * ws[OFF_OTTT + k];
        float pos = 0.f;
        #pragma unroll
        for (int k = 0; k < 10; k++) pos = (k == g) ? Sv[k] : pos;
        float hc = 0.f;
        #pragma unroll
        for (int k = 0; k < 10; k++)
            if (k != g) hc += fmaxf(pos - Sv[k] + MARGIN, 0.f);
        float hn = fmaxf(pos - Slast + MARGIN, 0.f);
        total = hc + hn + fabsf(Sgn - Slast);
    }
    #pragma unroll
    for (int off = 1; off < 64; off <<= 1) total += __shfl_xor(total, off);
    if (i == 0) out[0] = total * (1.0f / 64.0f);
}

extern "C" void kernel_launch(void* const* d_in, const int* in_sizes, int n_in,
                              void* d_out, int out_size, void* d_ws, size_t ws_size,
                              hipStream_t stream) {
    const float* anchor = (const float*)d_in[0];
    // d_in[1] = length_anchor (unused: encoded in weight zero-padding)
    const int*   grade  = (const int*)d_in[2];
    const float* weight = (const float*)d_in[3];
    const float* neg    = (const float*)d_in[4];
    const int*   gneg   = (const int*)d_in[5];
    const float* t0     = (const float*)d_in[6];
    // d_in[7] = num_class (hardcoded 10)
    float* ws  = (float*)d_ws;
    float* out = (float*)d_out;

    sq_kernel     <<<5821, 256, 0, stream>>>(anchor, neg, t0, ws);
    cost_kernel   <<<3594, 256, 0, stream>>>(anchor, neg, t0, gneg, ws);
    sinkhorn_lds  <<<842, 256, 0, stream>>>(weight, ws);
    sinkhorn_aa   <<<64, 1024, 0, stream>>>(weight, ws);
    assemble_kernel<<<1, 64, 0, stream>>>(grade, gneg, ws, out);
}